// Round 3
// baseline (191.698 us; speedup 1.0000x reference)
//
#include <hip/hip_runtime.h>

typedef __attribute__((ext_vector_type(8))) _Float16 f16x8;
typedef __attribute__((ext_vector_type(4))) float   f32x4;

namespace {
constexpr int kB    = 8192;
constexpr int kTH   = 11;
constexpr int kTP   = 80;
constexpr int kM    = 16;    // batch rows per wave (MFMA M)
constexpr int kStr  = 72;    // H-plane row stride in fp16 units (144 B, 16B-aligned)
}

// 8 fp32 -> fp16x8 (round-to-nearest)
__device__ __forceinline__ f16x8 cvt8(const float* f) {
    f16x8 v;
#pragma unroll
    for (int j = 0; j < 8; ++j) v[j] = (_Float16)f[j];
    return v;
}

// B-fragment pair for column `col`: B[k][col] = W[col][k], k-frags c=0,1.
__device__ __forceinline__ void loadB1(const float* __restrict__ W, int col, int q,
                                       f16x8 (&Bf)[2]) {
#pragma unroll
    for (int c = 0; c < 2; ++c) {
        const float* src = W + col * 64 + c * 32 + q * 8;
        const float4 a = reinterpret_cast<const float4*>(src)[0];
        const float4 b = reinterpret_cast<const float4*>(src)[1];
        float f[8] = {a.x, a.y, a.z, a.w, b.x, b.y, b.z, b.w};
        Bf[c] = cvt8(f);
    }
}

// fc B-fragment (col-tile 0 only): cols p<2 real (fcW is 2x64), others zero.
__device__ __forceinline__ void loadBfc(const float* __restrict__ fcW, int p, int q,
                                        f16x8 (&Bf)[2]) {
#pragma unroll
    for (int c = 0; c < 2; ++c) {
        float f[8];
#pragma unroll
        for (int j = 0; j < 8; ++j)
            f[j] = (p < 2) ? fcW[p * 64 + c * 32 + q * 8 + j] : 0.f;
        Bf[c] = cvt8(f);
    }
}

// G = w0 (x) fcW[0] + w1 (x) fcW[1]  (rank-2 folded feedback matrix), per column
__device__ __forceinline__ void loadBG(const float* __restrict__ fcW, float w0, float w1,
                                       int q, f16x8 (&Bf)[2]) {
#pragma unroll
    for (int c = 0; c < 2; ++c) {
        float f[8];
#pragma unroll
        for (int j = 0; j < 8; ++j) {
            const int k = c * 32 + q * 8 + j;
            f[j] = w0 * fcW[k] + w1 * fcW[64 + k];
        }
        Bf[c] = cvt8(f);
    }
}

__device__ __forceinline__ f16x8 read_frag(const _Float16* plane, int off) {
    return *reinterpret_cast<const f16x8*>(plane + off);
}

// single-term accumulate: D += A*B (A = fp16 h, B = fp16 W)
__device__ __forceinline__ f32x4 mfma1(f16x8 a, f16x8 b, f32x4 acc) {
    return __builtin_amdgcn_mfma_f32_16x16x32_f16(a, b, acc, 0, 0, 0);
}

// tanh via raw v_exp/v_rcp: 1 - 2*rcp(2^(2*log2e*x)+1); saturates safely.
__device__ __forceinline__ float fast_tanh(float x) {
    const float e = __builtin_amdgcn_exp2f(x * 2.8853900817779268f);  // 2/ln2
    return fmaf(-2.0f, __builtin_amdgcn_rcpf(e + 1.0f), 1.0f);
}

// R12 structure: 512 blocks x 1 wave; each wave owns 16 batch rows AND all 64
// hidden columns (4 col-tiles, full B matrices in registers, 8 MFMAs/product).
// The h1/h2 handoffs are within-wave LDS transposes -> ZERO barriers, zero
// inter-wave sync. Layout invariants identical to the verified R9 kernel:
//   C-frag:  value r of tile n = h[4q+r][p+16n]
//   A-frag:  frag c, elem j    = h[p][c*32 + q*8 + j]
//   B-frag:  loadB1(W, col=p+16n, q)
__global__ __launch_bounds__(64)
void traj_rnn_kernel(
    const float* __restrict__ x,
    const float* __restrict__ eWih0, const float* __restrict__ eWhh0,
    const float* __restrict__ ebih0, const float* __restrict__ ebhh0,
    const float* __restrict__ eWih1, const float* __restrict__ eWhh1,
    const float* __restrict__ ebih1, const float* __restrict__ ebhh1,
    const float* __restrict__ dWih0, const float* __restrict__ dWhh0,
    const float* __restrict__ dbih0, const float* __restrict__ dbhh0,
    const float* __restrict__ dWih1, const float* __restrict__ dWhh1,
    const float* __restrict__ dbih1, const float* __restrict__ dbhh1,
    const float* __restrict__ fcW, const float* __restrict__ fcb,
    float* __restrict__ out)
{
    const int lane = threadIdx.x;       // 0..63, single wave per block
    const int p    = lane & 15;         // C col-within-tile / A row
    const int q    = lane >> 4;         // C row-quad / A k-octet
    const int r0   = blockIdx.x * kM;

    __shared__ __align__(16) _Float16 h1buf[kM * kStr];
    __shared__ __align__(16) _Float16 h2buf[kM * kStr];
    __shared__ __align__(16) float xbuf[kM * kTH * 2];
    __shared__ __align__(16) float predbuf[kM * kTP * 2];

    for (int i = lane; i < kM * kTH * 2; i += 64)
        xbuf[i] = x[r0 * (kTH * 2) + i];
    // single wave: compiler-inserted lgkmcnt orders write->read; no barrier.

    const f16x8 Z = {0, 0, 0, 0, 0, 0, 0, 0};
    f16x8 H1f[2] = {Z, Z};
    f16x8 H2f[2] = {Z, Z};   // h2_0 = 0, consumed by first encoder a2-partial

    const int aoff = p * kStr;   // A-fragment base (row p)

    f32x4 P1[4];

    // ================= encoder: 11 steps =================
    {
        float b0[4], b1[4], w0[4], w1[4];
        f16x8 B0[8], B1[8], B2[8];
#pragma unroll
        for (int n = 0; n < 4; ++n) {
            const int col = p + 16 * n;
            b0[n] = ebih0[col] + ebhh0[col];
            b1[n] = ebih1[col] + ebhh1[col];
            w0[n] = eWih0[col * 2 + 0];
            w1[n] = eWih0[col * 2 + 1];
            f16x8 t[2];
            loadB1(eWhh0, col, q, t); B0[2 * n] = t[0]; B0[2 * n + 1] = t[1];
            loadB1(eWih1, col, q, t); B1[2 * n] = t[0]; B1[2 * n + 1] = t[1];
            loadB1(eWhh1, col, q, t); B2[2 * n] = t[0]; B2[2 * n + 1] = t[1];
        }
#pragma unroll
        for (int n = 0; n < 4; ++n) P1[n] = f32x4{b0[n], b0[n], b0[n], b0[n]};

#pragma unroll 1
        for (int t = 0; t < kTH; ++t) {
            // phase 1: h1 = tanh(P1 + x-term), write (C-layout -> LDS)
#pragma unroll
            for (int r = 0; r < 4; ++r) {
                const float2 xv = *reinterpret_cast<const float2*>(
                    &xbuf[(4 * q + r) * (kTH * 2) + 2 * t]);
#pragma unroll
                for (int n = 0; n < 4; ++n) {
                    const float h1 = fast_tanh(fmaf(w0[n], xv.x, fmaf(w1[n], xv.y, P1[n][r])));
                    h1buf[(4 * q + r) * kStr + p + 16 * n] = (_Float16)h1;
                }
            }
            // layer-2 partial on OLD H2 (covers h1 LDS latency)
            f32x4 a2[4];
#pragma unroll
            for (int n = 0; n < 4; ++n) a2[n] = f32x4{b1[n], b1[n], b1[n], b1[n]};
#pragma unroll
            for (int c = 0; c < 2; ++c)
#pragma unroll
                for (int n = 0; n < 4; ++n)
                    a2[n] = mfma1(H2f[c], B2[2 * n + c], a2[n]);
            // read h1 A-frags (within-wave transpose)
            H1f[0] = read_frag(h1buf, aoff + q * 8);
            H1f[1] = read_frag(h1buf, aoff + 32 + q * 8);
#pragma unroll
            for (int c = 0; c < 2; ++c)
#pragma unroll
                for (int n = 0; n < 4; ++n)
                    a2[n] = mfma1(H1f[c], B1[2 * n + c], a2[n]);
            // phase 2: h2 = tanh(a2), write; next-P1 partial covers latency
#pragma unroll
            for (int n = 0; n < 4; ++n)
#pragma unroll
                for (int r = 0; r < 4; ++r)
                    h2buf[(4 * q + r) * kStr + p + 16 * n] = (_Float16)fast_tanh(a2[n][r]);
            f32x4 np[4];
#pragma unroll
            for (int n = 0; n < 4; ++n) np[n] = f32x4{b0[n], b0[n], b0[n], b0[n]};
#pragma unroll
            for (int c = 0; c < 2; ++c)
#pragma unroll
                for (int n = 0; n < 4; ++n)
                    np[n] = mfma1(H1f[c], B0[2 * n + c], np[n]);
            H2f[0] = read_frag(h2buf, aoff + q * 8);
            H2f[1] = read_frag(h2buf, aoff + 32 + q * 8);
#pragma unroll
            for (int n = 0; n < 4; ++n) P1[n] = np[n];
        }
    }

    // ================= decoder: 80 autoregressive steps =================
    {
        float b1[4], w0[4], w1[4], b0p[4];
        f16x8 B0[8], B1[8], B2[8], BG[8], BF[2];
        const float fb0 = fcb[0];
        const float fb1 = fcb[1];
        const float fbp = (p == 0) ? fb0 : fb1;
        float b0[4];
#pragma unroll
        for (int n = 0; n < 4; ++n) {
            const int col = p + 16 * n;
            b0[n] = dbih0[col] + dbhh0[col];
            b1[n] = dbih1[col] + dbhh1[col];
            w0[n] = dWih0[col * 2 + 0];
            w1[n] = dWih0[col * 2 + 1];
            b0p[n] = b0[n] + w0[n] * fb0 + w1[n] * fb1;  // folded feedback bias
            f16x8 t[2];
            loadB1(dWhh0, col, q, t); B0[2 * n] = t[0]; B0[2 * n + 1] = t[1];
            loadB1(dWih1, col, q, t); B1[2 * n] = t[0]; B1[2 * n + 1] = t[1];
            loadB1(dWhh1, col, q, t); B2[2 * n] = t[0]; B2[2 * n + 1] = t[1];
            loadBG(fcW, w0[n], w1[n], q, t); BG[2 * n] = t[0]; BG[2 * n + 1] = t[1];
        }
        loadBfc(fcW, p, q, BF);

        // P1 for the FIRST decoder step: b0 + Whh0.h1_enc + w.x_last
#pragma unroll
        for (int n = 0; n < 4; ++n) P1[n] = f32x4{b0[n], b0[n], b0[n], b0[n]};
#pragma unroll
        for (int c = 0; c < 2; ++c)
#pragma unroll
            for (int n = 0; n < 4; ++n)
                P1[n] = mfma1(H1f[c], B0[2 * n + c], P1[n]);
#pragma unroll
        for (int r = 0; r < 4; ++r) {
            const float2 xv = *reinterpret_cast<const float2*>(
                &xbuf[(4 * q + r) * (kTH * 2) + 2 * (kTH - 1)]);
#pragma unroll
            for (int n = 0; n < 4; ++n)
                P1[n][r] = fmaf(w0[n], xv.x, fmaf(w1[n], xv.y, P1[n][r]));
        }

#pragma unroll 1
        for (int t = 0; t < kTP; ++t) {
            // phase 1: h1 = tanh(P1) (P1 already complete incl. folded feedback)
#pragma unroll
            for (int n = 0; n < 4; ++n)
#pragma unroll
                for (int r = 0; r < 4; ++r)
                    h1buf[(4 * q + r) * kStr + p + 16 * n] = (_Float16)fast_tanh(P1[n][r]);
            f32x4 a2[4];
#pragma unroll
            for (int n = 0; n < 4; ++n) a2[n] = f32x4{b1[n], b1[n], b1[n], b1[n]};
#pragma unroll
            for (int c = 0; c < 2; ++c)
#pragma unroll
                for (int n = 0; n < 4; ++n)
                    a2[n] = mfma1(H2f[c], B2[2 * n + c], a2[n]);   // old H2, covers latency
            H1f[0] = read_frag(h1buf, aoff + q * 8);
            H1f[1] = read_frag(h1buf, aoff + 32 + q * 8);
#pragma unroll
            for (int c = 0; c < 2; ++c)
#pragma unroll
                for (int n = 0; n < 4; ++n)
                    a2[n] = mfma1(H1f[c], B1[2 * n + c], a2[n]);
            // phase 2: h2 = tanh(a2), write; nb-partial covers latency
#pragma unroll
            for (int n = 0; n < 4; ++n)
#pragma unroll
                for (int r = 0; r < 4; ++r)
                    h2buf[(4 * q + r) * kStr + p + 16 * n] = (_Float16)fast_tanh(a2[n][r]);
            f32x4 nb[4];
#pragma unroll
            for (int n = 0; n < 4; ++n) nb[n] = f32x4{0.f, 0.f, 0.f, 0.f};
#pragma unroll
            for (int c = 0; c < 2; ++c)
#pragma unroll
                for (int n = 0; n < 4; ++n)
                    nb[n] = mfma1(H1f[c], B0[2 * n + c], nb[n]);
            H2f[0] = read_frag(h2buf, aoff + q * 8);
            H2f[1] = read_frag(h2buf, aoff + 32 + q * 8);
            // next-P1 feedback term (rank-2 folded G) + merge
#pragma unroll
            for (int n = 0; n < 4; ++n) {
                f32x4 ng = f32x4{b0p[n], b0p[n], b0p[n], b0p[n]};
#pragma unroll
                for (int c = 0; c < 2; ++c)
                    ng = mfma1(H2f[c], BG[2 * n + c], ng);
                P1[n] = ng + nb[n];
            }
            // fc head (col-tile 0 only; cols p<2 real)
            f32x4 fcC = f32x4{0.f, 0.f, 0.f, 0.f};
            fcC = mfma1(H2f[0], BF[0], fcC);
            fcC = mfma1(H2f[1], BF[1], fcC);
            if (p < 2) {
#pragma unroll
                for (int r = 0; r < 4; ++r)
                    predbuf[((4 * q + r) * kTP + t) * 2 + p] = fcC[r] + fbp;
            }
        }
    }

    // flush preds: wave covers out[r0*160 .. (r0+16)*160), contiguous & aligned
    {
        float4* dst = reinterpret_cast<float4*>(out + r0 * (kTP * 2));
        const float4* src = reinterpret_cast<const float4*>(predbuf);
#pragma unroll 1
        for (int i = lane; i < kM * kTP * 2 / 4; i += 64)
            dst[i] = src[i];
    }
}

extern "C" void kernel_launch(void* const* d_in, const int* in_sizes, int n_in,
                              void* d_out, int out_size, void* d_ws, size_t ws_size,
                              hipStream_t stream) {
    const float* x     = (const float*)d_in[0];
    const float* eWih0 = (const float*)d_in[1];
    const float* eWhh0 = (const float*)d_in[2];
    const float* ebih0 = (const float*)d_in[3];
    const float* ebhh0 = (const float*)d_in[4];
    const float* eWih1 = (const float*)d_in[5];
    const float* eWhh1 = (const float*)d_in[6];
    const float* ebih1 = (const float*)d_in[7];
    const float* ebhh1 = (const float*)d_in[8];
    const float* dWih0 = (const float*)d_in[9];
    const float* dWhh0 = (const float*)d_in[10];
    const float* dbih0 = (const float*)d_in[11];
    const float* dbhh0 = (const float*)d_in[12];
    const float* dWih1 = (const float*)d_in[13];
    const float* dWhh1 = (const float*)d_in[14];
    const float* dbih1 = (const float*)d_in[15];
    const float* dbhh1 = (const float*)d_in[16];
    const float* fcW   = (const float*)d_in[17];
    const float* fcb   = (const float*)d_in[18];
    float* out = (float*)d_out;

    dim3 grid(kB / kM);   // 512 single-wave blocks; 2 waves/CU, zero barriers
    dim3 block(64);
    traj_rnn_kernel<<<grid, block, 0, stream>>>(
        x, eWih0, eWhh0, ebih0, ebhh0, eWih1, eWhh1, ebih1, ebhh1,
        dWih0, dWhh0, dbih0, dbhh0, dWih1, dWhh1, dbih1, dbhh1,
        fcW, fcb, out);
}

// Round 4
// 144.876 us; speedup vs baseline: 1.3232x; 1.3232x over previous
//
#include <hip/hip_runtime.h>

typedef __attribute__((ext_vector_type(8))) _Float16 f16x8;
typedef __attribute__((ext_vector_type(4))) float   f32x4;

namespace {
constexpr int kB    = 8192;
constexpr int kTH   = 11;
constexpr int kTP   = 80;
constexpr int kM    = 16;    // batch rows per block (MFMA M)
constexpr int kStrH = 72;    // H-plane row stride in fp16 units (144 B: 16B-aligned)
}

// 8 fp32 -> fp16x8 (round-to-nearest)
__device__ __forceinline__ f16x8 cvt8(const float* f) {
    f16x8 v;
#pragma unroll
    for (int j = 0; j < 8; ++j) v[j] = (_Float16)f[j];
    return v;
}

// B-fragment (single fp16) for column `col`: B[k][col] = W[col][k].
__device__ __forceinline__ void loadB1(const float* __restrict__ W, int col, int q,
                                       f16x8 (&Bf)[2]) {
#pragma unroll
    for (int c = 0; c < 2; ++c) {
        const float* src = W + col * 64 + c * 32 + q * 8;
        const float4 a = reinterpret_cast<const float4*>(src)[0];
        const float4 b = reinterpret_cast<const float4*>(src)[1];
        float f[8] = {a.x, a.y, a.z, a.w, b.x, b.y, b.z, b.w};
        Bf[c] = cvt8(f);
    }
}

// fc B-fragment: only cols p<2 are real (fcW is 2x64); others zero.
__device__ __forceinline__ void loadBfc(const float* __restrict__ fcW, int p, int q,
                                        f16x8 (&Bf)[2]) {
#pragma unroll
    for (int c = 0; c < 2; ++c) {
        float f[8];
#pragma unroll
        for (int j = 0; j < 8; ++j)
            f[j] = (p < 2) ? fcW[p * 64 + c * 32 + q * 8 + j] : 0.f;
        Bf[c] = cvt8(f);
    }
}

// G = w0 (x) fcW[0] + w1 (x) fcW[1]  (rank-2 folded feedback matrix)
__device__ __forceinline__ void loadBG(const float* __restrict__ fcW, float w0, float w1,
                                       int q, f16x8 (&Bf)[2]) {
#pragma unroll
    for (int c = 0; c < 2; ++c) {
        float f[8];
#pragma unroll
        for (int j = 0; j < 8; ++j) {
            const int k = c * 32 + q * 8 + j;
            f[j] = w0 * fcW[k] + w1 * fcW[64 + k];
        }
        Bf[c] = cvt8(f);
    }
}

__device__ __forceinline__ f16x8 read_frag(const _Float16* plane, int off) {
    return *reinterpret_cast<const f16x8*>(plane + off);
}

// single-term accumulate: D += A*B (A = fp16 h, B = fp16 W)
__device__ __forceinline__ f32x4 mfma1(f16x8 a, f16x8 b, f32x4 acc) {
    return __builtin_amdgcn_mfma_f32_16x16x32_f16(a, b, acc, 0, 0, 0);
}

// tanh via raw v_exp/v_rcp: 1 - 2*rcp(2^(2*log2e*x)+1); saturates safely.
__device__ __forceinline__ float fast_tanh(float x) {
    const float e = __builtin_amdgcn_exp2f(x * 2.8853900817779268f);  // 2/ln2
    return fmaf(-2.0f, __builtin_amdgcn_rcpf(e + 1.0f), 1.0f);
}

// R13 = R9 structure (512 blocks x 4 waves, 2 blocks/CU, 2 waves/SIMD)
//  + setprio phasing: prio 1 over cross-wave-critical segments, 0 over fillers
//    (anti-convoy arbitration between the two co-resident blocks)
//  + one-time start stagger for odd-parity blocks (seed anti-phase)
//  + nb-hoist into the post-bar1 slot (shorter phase-3 chain, fatter filler)
// Arithmetic is bit-identical to R9.
__global__ __attribute__((amdgpu_waves_per_eu(2, 2))) __launch_bounds__(256)
void traj_rnn_kernel(
    const float* __restrict__ x,
    const float* __restrict__ eWih0, const float* __restrict__ eWhh0,
    const float* __restrict__ ebih0, const float* __restrict__ ebhh0,
    const float* __restrict__ eWih1, const float* __restrict__ eWhh1,
    const float* __restrict__ ebih1, const float* __restrict__ ebhh1,
    const float* __restrict__ dWih0, const float* __restrict__ dWhh0,
    const float* __restrict__ dbih0, const float* __restrict__ dbhh0,
    const float* __restrict__ dWih1, const float* __restrict__ dWhh1,
    const float* __restrict__ dbih1, const float* __restrict__ dbhh1,
    const float* __restrict__ fcW, const float* __restrict__ fcb,
    float* __restrict__ out)
{
    const int tid  = threadIdx.x;
    const int wv   = tid >> 6;          // n-tile owned by this wave (0..3)
    const int lane = tid & 63;
    const int p    = lane & 15;         // A-m / C-col-within-tile
    const int q    = lane >> 4;         // k-quad / C row-quad
    const int col  = wv * 16 + p;       // this lane's hidden-unit column
    const int r0   = blockIdx.x * kM;

    __shared__ __align__(16) _Float16 Hhi1[kM * kStrH];
    __shared__ __align__(16) _Float16 Hhi2[kM * kStrH];
    __shared__ __align__(16) float xbuf[kM * kTH * 2];
    __shared__ __align__(16) float predbuf[kM * kTP * 2];  // preds staged; flushed once

    for (int i = tid; i < kM * kTH * 2; i += 256)
        xbuf[i] = x[r0 * (kTH * 2) + i];

    f16x8 H1f[2], H2f[2];
#pragma unroll
    for (int c = 0; c < 2; ++c) {
        H1f[c] = f16x8{0, 0, 0, 0, 0, 0, 0, 0};
        H2f[c] = f16x8{0, 0, 0, 0, 0, 0, 0, 0};
    }
    __syncthreads();

    // anti-convoy stagger: odd-parity blocks (parity over bits 0/3/8 so any
    // plausible co-resident pairing i,i+1 / i,i+8 / i,i+256 differs) sleep
    // ~900 cycles once, seeding anti-phase between the CU's two blocks.
    if ((blockIdx.x ^ (blockIdx.x >> 3) ^ (blockIdx.x >> 8)) & 1) {
        __builtin_amdgcn_s_sleep(7);
        __builtin_amdgcn_s_sleep(7);
    }

    const int aoff = p * kStrH;  // A-fragment base for this lane's m-row

    // ================= encoder: 11 steps =================
    {
        const float b0 = ebih0[col] + ebhh0[col];
        const float b1 = ebih1[col] + ebhh1[col];
        const float w0 = eWih0[col * 2 + 0];
        const float w1 = eWih0[col * 2 + 1];
        f16x8 B0[2], B1[2], B2[2];
        loadB1(eWhh0, col, q, B0);   // Whh0
        loadB1(eWih1, col, q, B1);   // Wih1
        loadB1(eWhh1, col, q, B2);   // Whh1

        f32x4 P1 = {b0, b0, b0, b0};       // b0 + Whh0 . h1 (h1 = 0 initially)

#pragma unroll 1
        for (int t = 0; t < kTH; ++t) {
            // [critical] h1 = tanh(P1 + x-term), write
            __builtin_amdgcn_s_setprio(1);
#pragma unroll
            for (int r = 0; r < 4; ++r) {
                const float2 xv = *reinterpret_cast<const float2*>(
                    &xbuf[(4 * q + r) * (kTH * 2) + 2 * t]);
                const float h1 = fast_tanh(fmaf(w0, xv.x, fmaf(w1, xv.y, P1[r])));
                Hhi1[(4 * q + r) * kStrH + col] = (_Float16)h1;
            }
            __builtin_amdgcn_s_setprio(0);
            // [filler] layer-2 partial on OLD H2
            f32x4 a2 = {b1, b1, b1, b1};
            a2 = mfma1(H2f[0], B2[0], a2);
            a2 = mfma1(H2f[1], B2[1], a2);
            __syncthreads();   // h1' visible

            // [critical] read h1 frags, finish a2, produce h2'
            __builtin_amdgcn_s_setprio(1);
            H1f[0] = read_frag(Hhi1, aoff + q * 8);
            H1f[1] = read_frag(Hhi1, aoff + 32 + q * 8);
            a2 = mfma1(H1f[0], B1[0], a2);
            a2 = mfma1(H1f[1], B1[1], a2);
#pragma unroll
            for (int r = 0; r < 4; ++r) {
                const float h2 = fast_tanh(a2[r]);
                Hhi2[(4 * q + r) * kStrH + col] = (_Float16)h2;
            }
            __builtin_amdgcn_s_setprio(0);
            // [filler] next-P1 recurrent term (H1 frags live)
            f32x4 np = {b0, b0, b0, b0};
            np = mfma1(H1f[0], B0[0], np);
            np = mfma1(H1f[1], B0[1], np);
            __syncthreads();   // h2' visible

            // [critical] read h2 frags for next a2-partial
            __builtin_amdgcn_s_setprio(1);
            H2f[0] = read_frag(Hhi2, aoff + q * 8);
            H2f[1] = read_frag(Hhi2, aoff + 32 + q * 8);
            __builtin_amdgcn_s_setprio(0);
            P1 = np;
        }
    }

    // ================= decoder: 80 autoregressive steps =================
    {
        const float b0 = dbih0[col] + dbhh0[col];
        const float b1 = dbih1[col] + dbhh1[col];
        const float w0 = dWih0[col * 2 + 0];
        const float w1 = dWih0[col * 2 + 1];
        const float fb0 = fcb[0];
        const float fb1 = fcb[1];
        // folded bias: feedback constant term absorbed into layer-1 bias
        const float b0p = b0 + w0 * fb0 + w1 * fb1;
        const float fbp = (p == 0) ? fb0 : fb1;   // for LDS stash from p<2 lanes
        f16x8 B0[2], B1[2], B2[2], BF[2], BG[2];
        loadB1(dWhh0, col, q, B0);
        loadB1(dWih1, col, q, B1);
        loadB1(dWhh1, col, q, B2);
        loadBfc(fcW, p, q, BF);
        loadBG(fcW, w0, w1, q, BG);   // rank-2 folded feedback matrix

        // P1 for the FIRST decoder step: b0 + Whh0.h1_enc + w0*x_last0 + w1*x_last1
        f32x4 P1 = {b0, b0, b0, b0};
        P1 = mfma1(H1f[0], B0[0], P1);
        P1 = mfma1(H1f[1], B0[1], P1);
#pragma unroll
        for (int r = 0; r < 4; ++r) {
            const float2 xv = *reinterpret_cast<const float2*>(
                &xbuf[(4 * q + r) * (kTH * 2) + 2 * (kTH - 1)]);
            P1[r] = fmaf(w0, xv.x, fmaf(w1, xv.y, P1[r]));
        }

#pragma unroll 2
        for (int t = 0; t < kTP; ++t) {
            // [critical] h1 = tanh(P1), write (P1 complete incl. folded feedback)
            __builtin_amdgcn_s_setprio(1);
#pragma unroll
            for (int r = 0; r < 4; ++r) {
                const float h1 = fast_tanh(P1[r]);
                Hhi1[(4 * q + r) * kStrH + col] = (_Float16)h1;
            }
            __builtin_amdgcn_s_setprio(0);
            // [filler] layer-2 partial on OLD H2
            f32x4 a2 = {b1, b1, b1, b1};
            a2 = mfma1(H2f[0], B2[0], a2);
            a2 = mfma1(H2f[1], B2[1], a2);
            __syncthreads();   // h1' visible

            // [critical] read h1 frags, finish a2, produce h2'
            __builtin_amdgcn_s_setprio(1);
            H1f[0] = read_frag(Hhi1, aoff + q * 8);
            H1f[1] = read_frag(Hhi1, aoff + 32 + q * 8);
            a2 = mfma1(H1f[0], B1[0], a2);
            a2 = mfma1(H1f[1], B1[1], a2);
#pragma unroll
            for (int r = 0; r < 4; ++r) {
                const float h2 = fast_tanh(a2[r]);
                Hhi2[(4 * q + r) * kStrH + col] = (_Float16)h2;
            }
            __builtin_amdgcn_s_setprio(0);
            // [filler] nb = B0.h1 (hoisted from phase 3; operand live here)
            f32x4 nb = {0.f, 0.f, 0.f, 0.f};
            nb = mfma1(H1f[0], B0[0], nb);
            nb = mfma1(H1f[1], B0[1], nb);
            __syncthreads();   // h2' visible

            // [critical] read h2 frags, feedback term, next P1
            __builtin_amdgcn_s_setprio(1);
            H2f[0] = read_frag(Hhi2, aoff + q * 8);
            H2f[1] = read_frag(Hhi2, aoff + 32 + q * 8);
            f32x4 ng = {b0p, b0p, b0p, b0p};
            ng = mfma1(H2f[0], BG[0], ng);
            ng = mfma1(H2f[1], BG[1], ng);
            P1 = ng + nb;
            __builtin_amdgcn_s_setprio(0);

            // [filler] fc on all waves (balanced); only wave 0 p<2 stores
            f32x4 fcC = {0.f, 0.f, 0.f, 0.f};
            fcC = mfma1(H2f[0], BF[0], fcC);
            fcC = mfma1(H2f[1], BF[1], fcC);
            if (wv == 0 && p < 2) {
#pragma unroll
                for (int r = 0; r < 4; ++r)
                    predbuf[((4 * q + r) * kTP + t) * 2 + p] = fcC[r] + fbp;
            }
        }
    }

    // flush preds: block covers out[r0*kTP*2 .. (r0+16)*kTP*2), contiguous & aligned
    __syncthreads();
    {
        float4* dst = reinterpret_cast<float4*>(out + r0 * (kTP * 2));
        const float4* src = reinterpret_cast<const float4*>(predbuf);
        for (int i = tid; i < kM * kTP * 2 / 4; i += 256)
            dst[i] = src[i];
    }
}

extern "C" void kernel_launch(void* const* d_in, const int* in_sizes, int n_in,
                              void* d_out, int out_size, void* d_ws, size_t ws_size,
                              hipStream_t stream) {
    const float* x     = (const float*)d_in[0];
    const float* eWih0 = (const float*)d_in[1];
    const float* eWhh0 = (const float*)d_in[2];
    const float* ebih0 = (const float*)d_in[3];
    const float* ebhh0 = (const float*)d_in[4];
    const float* eWih1 = (const float*)d_in[5];
    const float* eWhh1 = (const float*)d_in[6];
    const float* ebih1 = (const float*)d_in[7];
    const float* ebhh1 = (const float*)d_in[8];
    const float* dWih0 = (const float*)d_in[9];
    const float* dWhh0 = (const float*)d_in[10];
    const float* dbih0 = (const float*)d_in[11];
    const float* dbhh0 = (const float*)d_in[12];
    const float* dWih1 = (const float*)d_in[13];
    const float* dWhh1 = (const float*)d_in[14];
    const float* dbih1 = (const float*)d_in[15];
    const float* dbhh1 = (const float*)d_in[16];
    const float* fcW   = (const float*)d_in[17];
    const float* fcb   = (const float*)d_in[18];
    float* out = (float*)d_out;

    dim3 grid(kB / kM);   // 512 blocks x 4 waves; wave n owns output cols 16n..16n+15
    dim3 block(256);
    traj_rnn_kernel<<<grid, block, 0, stream>>>(
        x, eWih0, eWhh0, ebih0, ebhh0, eWih1, eWhh1, ebih1, ebhh1,
        dWih0, dWhh0, dbih0, dbhh0, dWih1, dWhh1, dbih1, dbhh1,
        fcW, fcb, out);
}